// Round 19
// baseline (247.941 us; speedup 1.0000x reference)
//
#include <hip/hip_runtime.h>
#include <cstdint>
#include <cstddef>

#define GN 16384          // nodes
#define GF 64             // features
#define NW (GN / 32)      // 512 words per column (logical)

typedef __bf16 bf16x8 __attribute__((ext_vector_type(8)));
typedef float f32x4 __attribute__((ext_vector_type(4)));
typedef unsigned int u32x4 __attribute__((ext_vector_type(4)));

// R2/R6/R7-validated cheap decode.
__device__ __forceinline__ bf16x8 decode8(unsigned int b) {
  unsigned int t = (b & 0xffu) * 0x8001u;
  u32x4 r;
  r[0] = (t & 0x00010001u) * 0x3F80u;
  r[1] = ((t >> 2) & 0x00010001u) * 0x3F80u;
  r[2] = ((t >> 4) & 0x00010001u) * 0x3F80u;
  r[3] = ((t >> 6) & 0x00010001u) * 0x3F80u;
  return __builtin_bit_cast(bf16x8, r);
}

__device__ __forceinline__ unsigned short f2bf(float v) {  // RNE f32->bf16
  unsigned int u = __builtin_bit_cast(unsigned int, v);
  u += 0x7fffu + ((u >> 16) & 1u);
  return (unsigned short)(u >> 16);
}

__device__ __forceinline__ float bf2f(unsigned short s) {
  return __builtin_bit_cast(float, (unsigned int)s << 16);
}

// ---------------------------------------------------------------------------
// K1 v9: R17's structure at 4 BLOCKS/CU. Grid 1024 = 16 col-blocks x 64
// row-blocks; block = 256 rows x 1024 cols = quads jb*2 + seg (seg=0..1).
// Packed layout/content bit-identical to R17 quad-major. Deg atomics same
// (64 exact-int partials instead of 32 -> same sum). 2x read-streams/SIMD.
// ---------------------------------------------------------------------------
__global__ __launch_bounds__(256) void k_pack(const float* __restrict__ adj,
                                              float* __restrict__ deg,
                                              unsigned int* __restrict__ packed) {
  const int cb = blockIdx.x >> 6;      // 0..15
  const int jb = blockIdx.x & 63;      // 0..63
  const int col0 = cb * 1024 + (int)threadIdx.x * 4;
  const int j0 = jb * 256;
  int cnt0 = 0, cnt1 = 0, cnt2 = 0, cnt3 = 0;

  u32x4 vv0[2], vv1[2], vv2[2], vv3[2];

#pragma unroll
  for (int seg = 0; seg < 2; ++seg) {
#pragma unroll
    for (int q = 0; q < 4; ++q) {
      unsigned int w0 = 0, w1 = 0, w2 = 0, w3 = 0;
      const float* base = adj + (size_t)(j0 + seg * 128 + q * 32) * GN + col0;
#pragma unroll 8
      for (int b = 0; b < 32; ++b) {
        f32x4 a = *(const f32x4*)(base + (size_t)b * GN);
        unsigned int m = 1u << b;
        if (a.x != 0.f) w0 |= m;
        if (a.y != 0.f) w1 |= m;
        if (a.z != 0.f) w2 |= m;
        if (a.w != 0.f) w3 |= m;
      }
      vv0[seg][q] = w0; vv1[seg][q] = w1; vv2[seg][q] = w2; vv3[seg][q] = w3;
      cnt0 += __popc(w0); cnt1 += __popc(w1); cnt2 += __popc(w2); cnt3 += __popc(w3);
    }
  }
  // quad-major stores (bit-identical layout to R17)
#pragma unroll
  for (int seg = 0; seg < 2; ++seg) {
    unsigned int* q0 = packed + ((size_t)(jb * 2 + seg) * GN + col0) * 4;
    *(u32x4*)(q0 + 0)  = vv0[seg];
    *(u32x4*)(q0 + 4)  = vv1[seg];
    *(u32x4*)(q0 + 8)  = vv2[seg];
    *(u32x4*)(q0 + 12) = vv3[seg];
  }

  atomicAdd(&deg[col0 + 0], (float)cnt0);
  atomicAdd(&deg[col0 + 1], (float)cnt1);
  atomicAdd(&deg[col0 + 2], (float)cnt2);
  atomicAdd(&deg[col0 + 3], (float)cnt3);
}

// ---------------------------------------------------------------------------
// K2 (byte-identical to R16/R17): z row-major bf16 + lane-linear chunked z2.
// ---------------------------------------------------------------------------
__global__ __launch_bounds__(256) void k_z(const float* __restrict__ x,
                                           const float* __restrict__ W,
                                           const float* __restrict__ deg,
                                           float* __restrict__ dinv,
                                           unsigned short* __restrict__ z_rm,
                                           unsigned short* __restrict__ z2) {
  __shared__ float Wl[64][64];
  __shared__ float xl[64][64];
  const int tid = threadIdx.x;
  const int f = tid & 63;
  const int w = tid >> 6;
  const int rowB = blockIdx.x * 64;

  for (int idx = tid; idx < 4096; idx += 256) {
    Wl[idx >> 6][idx & 63] = W[idx];
    xl[idx >> 6][idx & 63] = x[(size_t)rowB * 64 + idx];
  }
  __syncthreads();

  float acc[16];
#pragma unroll
  for (int r = 0; r < 16; ++r) acc[r] = 0.f;
  for (int k = 0; k < 64; ++k) {
    float wk = Wl[k][f];
#pragma unroll
    for (int r = 0; r < 16; ++r) acc[r] = fmaf(xl[w * 16 + r][k], wk, acc[r]);
  }

  const int row0 = rowB + w * 16;
  if (f < 16) {
    int row = row0 + f;
    dinv[row] = 1.0f / sqrtf(deg[row] + 1.0f);
  }

  unsigned short zs[16];
#pragma unroll
  for (int r = 0; r < 16; ++r) {
    int row = row0 + r;
    float di = 1.0f / sqrtf(deg[row] + 1.0f);
    unsigned short zb = f2bf(di * acc[r]);
    zs[r] = zb;
    z_rm[(size_t)row * GF + f] = zb;
  }
  unsigned int p[8];
#pragma unroll
  for (int i = 0; i < 8; ++i)
    p[i] = (unsigned int)zs[2 * i] | ((unsigned int)zs[2 * i + 1] << 16);
  // lane-linear layout: kb = 2*(w&1) + (r>>3), e = r&7
  char* dst = (char*)z2 + (size_t)((rowB >> 5) + (w >> 1)) * 4096 +
              (f >> 4) * 1024 + ((2 * (w & 1)) * 16 + (f & 15)) * 16;
  u32x4 lo = {p[0], p[1], p[2], p[3]};
  u32x4 hi = {p[4], p[5], p[6], p[7]};
  *(u32x4*)dst = lo;          // kb = 2*(w&1)     (r 0..7)
  *(u32x4*)(dst + 256) = hi;  // kb = 2*(w&1) + 1 (r 8..15)
}

// ---------------------------------------------------------------------------
// K3 (byte-identical to R17 v13): setprio + lane-linear z2 + quad-major bits.
// ---------------------------------------------------------------------------
__global__ __launch_bounds__(512) void k_spmm(const unsigned int* __restrict__ packed,
                                              const unsigned short* __restrict__ z2,
                                              const unsigned short* __restrict__ z_rm,
                                              const float* __restrict__ dinv,
                                              const float* __restrict__ bias,
                                              float* __restrict__ out) {
  __shared__ float red[4][64][64];  // 64 KB
  const int i0 = blockIdx.x * 64;
  const int tid = threadIdx.x;
  const int wid = tid >> 6, lane = tid & 63;
  const int lrow = lane & 15, kb = lane >> 4;
  const int sh = kb * 8;

  f32x4 acc[4][4];
#pragma unroll
  for (int m = 0; m < 4; ++m)
#pragma unroll
    for (int n = 0; n < 4; ++n) acc[m][n] = (f32x4){0.f, 0.f, 0.f, 0.f};

  const size_t qstep = (size_t)GN * 4;  // dwords per quad-row
  const unsigned int* pr0 = packed + (size_t)(wid * 16) * qstep / 4 * 4 +
                            (size_t)(i0 + 0 * 16 + lrow) * 4;
  const unsigned int* pr1 = packed + (size_t)(wid * 16) * qstep / 4 * 4 +
                            (size_t)(i0 + 1 * 16 + lrow) * 4;
  const unsigned int* pr2 = packed + (size_t)(wid * 16) * qstep / 4 * 4 +
                            (size_t)(i0 + 2 * 16 + lrow) * 4;
  const unsigned int* pr3 = packed + (size_t)(wid * 16) * qstep / 4 * 4 +
                            (size_t)(i0 + 3 * 16 + lrow) * 4;
  const char* zbase = (const char*)z2 + (size_t)(wid * 64) * 4096 + lane * 16;

  bf16x8 cur0 = *(const bf16x8*)(zbase + 0 * 1024);
  bf16x8 cur1 = *(const bf16x8*)(zbase + 1 * 1024);
  bf16x8 cur2 = *(const bf16x8*)(zbase + 2 * 1024);
  bf16x8 cur3 = *(const bf16x8*)(zbase + 3 * 1024);
  u32x4 bits0 = *(const u32x4*)pr0;
  u32x4 bits1 = *(const u32x4*)pr1;
  u32x4 bits2 = *(const u32x4*)pr2;
  u32x4 bits3 = *(const u32x4*)pr3;

  for (int it = 0; it < 16; ++it) {
    u32x4 nb0 = *(const u32x4*)(pr0 + qstep);
    u32x4 nb1 = *(const u32x4*)(pr1 + qstep);
    u32x4 nb2 = *(const u32x4*)(pr2 + qstep);
    u32x4 nb3 = *(const u32x4*)(pr3 + qstep);
#pragma unroll
    for (int s = 0; s < 4; ++s) {
      const char* zn = zbase + (s + 1) * 4096;
      bf16x8 n0 = *(const bf16x8*)(zn + 0 * 1024);
      bf16x8 n1 = *(const bf16x8*)(zn + 1 * 1024);
      bf16x8 n2 = *(const bf16x8*)(zn + 2 * 1024);
      bf16x8 n3 = *(const bf16x8*)(zn + 3 * 1024);

      __builtin_amdgcn_s_setprio(1);
      bf16x8 a0 = decode8(bits0[s] >> sh);
      acc[0][0] = __builtin_amdgcn_mfma_f32_16x16x32_bf16(a0, cur0, acc[0][0], 0, 0, 0);
      acc[0][1] = __builtin_amdgcn_mfma_f32_16x16x32_bf16(a0, cur1, acc[0][1], 0, 0, 0);
      acc[0][2] = __builtin_amdgcn_mfma_f32_16x16x32_bf16(a0, cur2, acc[0][2], 0, 0, 0);
      acc[0][3] = __builtin_amdgcn_mfma_f32_16x16x32_bf16(a0, cur3, acc[0][3], 0, 0, 0);
      bf16x8 a1 = decode8(bits1[s] >> sh);
      acc[1][0] = __builtin_amdgcn_mfma_f32_16x16x32_bf16(a1, cur0, acc[1][0], 0, 0, 0);
      acc[1][1] = __builtin_amdgcn_mfma_f32_16x16x32_bf16(a1, cur1, acc[1][1], 0, 0, 0);
      acc[1][2] = __builtin_amdgcn_mfma_f32_16x16x32_bf16(a1, cur2, acc[1][2], 0, 0, 0);
      acc[1][3] = __builtin_amdgcn_mfma_f32_16x16x32_bf16(a1, cur3, acc[1][3], 0, 0, 0);
      bf16x8 a2 = decode8(bits2[s] >> sh);
      acc[2][0] = __builtin_amdgcn_mfma_f32_16x16x32_bf16(a2, cur0, acc[2][0], 0, 0, 0);
      acc[2][1] = __builtin_amdgcn_mfma_f32_16x16x32_bf16(a2, cur1, acc[2][1], 0, 0, 0);
      acc[2][2] = __builtin_amdgcn_mfma_f32_16x16x32_bf16(a2, cur2, acc[2][2], 0, 0, 0);
      acc[2][3] = __builtin_amdgcn_mfma_f32_16x16x32_bf16(a2, cur3, acc[2][3], 0, 0, 0);
      bf16x8 a3 = decode8(bits3[s] >> sh);
      acc[3][0] = __builtin_amdgcn_mfma_f32_16x16x32_bf16(a3, cur0, acc[3][0], 0, 0, 0);
      acc[3][1] = __builtin_amdgcn_mfma_f32_16x16x32_bf16(a3, cur1, acc[3][1], 0, 0, 0);
      acc[3][2] = __builtin_amdgcn_mfma_f32_16x16x32_bf16(a3, cur2, acc[3][2], 0, 0, 0);
      acc[3][3] = __builtin_amdgcn_mfma_f32_16x16x32_bf16(a3, cur3, acc[3][3], 0, 0, 0);
      __builtin_amdgcn_s_setprio(0);

      cur0 = n0; cur1 = n1; cur2 = n2; cur3 = n3;
    }
    bits0 = nb0; bits1 = nb1; bits2 = nb2; bits3 = nb3;
    pr0 += qstep; pr1 += qstep; pr2 += qstep; pr3 += qstep;
    zbase += 16384;
  }

  if (wid < 4) {
#pragma unroll
    for (int m = 0; m < 4; ++m)
#pragma unroll
      for (int n = 0; n < 4; ++n)
#pragma unroll
        for (int r = 0; r < 4; ++r)
          red[wid][m * 16 + kb * 4 + r][n * 16 + lrow] = acc[m][n][r];
  }
  __syncthreads();
  if (wid >= 4) {
#pragma unroll
    for (int m = 0; m < 4; ++m)
#pragma unroll
      for (int n = 0; n < 4; ++n)
#pragma unroll
        for (int r = 0; r < 4; ++r)
          red[wid - 4][m * 16 + kb * 4 + r][n * 16 + lrow] += acc[m][n][r];
  }
  __syncthreads();

  const int c = tid & 63;
  const int rg = tid >> 6;
  const float bc = bias[c];
#pragma unroll
  for (int rr = 0; rr < 8; ++rr) {
    int r = rg * 8 + rr;
    int i = i0 + r;
    float s = red[0][r][c] + red[1][r][c] + red[2][r][c] + red[3][r][c];
    float o = dinv[i] * (s + bf2f(z_rm[(size_t)i * GF + c])) + bc;
    out[(size_t)i * GF + c] = fmaxf(o, 0.f);
  }
}

// ---------------------------------------------------------------------------
extern "C" void kernel_launch(void* const* d_in, const int* in_sizes, int n_in,
                              void* d_out, int out_size, void* d_ws, size_t ws_size,
                              hipStream_t stream) {
  const float* x = (const float*)d_in[0];
  const float* adj = (const float*)d_in[1];
  const float* W = (const float*)d_in[2];
  const float* bias = (const float*)d_in[3];
  float* out = (float*)d_out;

  char* ws = (char*)d_ws;
  float* deg = (float*)ws;                                        // 64 KB
  float* dinv = (float*)(ws + 65536);                             // 64 KB
  unsigned short* z_rm = (unsigned short*)(ws + 131072);          // 2 MB
  unsigned short* z2 = (unsigned short*)(ws + 131072 + 2097152);  // 2 MB lane-linear
  unsigned int* packed = (unsigned int*)(ws + 131072 + 4194304);  // 32 MB quad-major
  // need: 131072 + 4 MB + 32 MB + 512 KB tail-prefetch slack = 38,928,384 B
  if (ws_size < 38928384u) return;

  hipMemsetAsync(deg, 0, GN * sizeof(float), stream);
  k_pack<<<dim3(1024), dim3(256), 0, stream>>>(adj, deg, packed);
  k_z<<<dim3(GN / 64), dim3(256), 0, stream>>>(x, W, deg, dinv, z_rm, z2);
  k_spmm<<<dim3(GN / 64), dim3(512), 0, stream>>>(packed, z2, z_rm, dinv, bias, out);
}

// Round 20
// 237.212 us; speedup vs baseline: 1.0452x; 1.0452x over previous
//
#include <hip/hip_runtime.h>
#include <cstdint>
#include <cstddef>

#define GN 16384          // nodes
#define GF 64             // features
#define NW (GN / 32)      // 512 words per column (logical)

typedef __bf16 bf16x8 __attribute__((ext_vector_type(8)));
typedef float f32x4 __attribute__((ext_vector_type(4)));
typedef unsigned int u32x4 __attribute__((ext_vector_type(4)));

// R2/R6/R7-validated cheap decode.
__device__ __forceinline__ bf16x8 decode8(unsigned int b) {
  unsigned int t = (b & 0xffu) * 0x8001u;
  u32x4 r;
  r[0] = (t & 0x00010001u) * 0x3F80u;
  r[1] = ((t >> 2) & 0x00010001u) * 0x3F80u;
  r[2] = ((t >> 4) & 0x00010001u) * 0x3F80u;
  r[3] = ((t >> 6) & 0x00010001u) * 0x3F80u;
  return __builtin_bit_cast(bf16x8, r);
}

__device__ __forceinline__ unsigned short f2bf(float v) {  // RNE f32->bf16
  unsigned int u = __builtin_bit_cast(unsigned int, v);
  u += 0x7fffu + ((u >> 16) & 1u);
  return (unsigned short)(u >> 16);
}

__device__ __forceinline__ float bf2f(unsigned short s) {
  return __builtin_bit_cast(float, (unsigned int)s << 16);
}

// ---------------------------------------------------------------------------
// K1 v7 (R17, best measured): reads/compute/atomics as R7; packed store
// layout QUAD-MAJOR: packed[(wq*GN + col)*4 + q] = word wq*4+q of column col.
// Wave-wide per seg: 64 threads x 64 B = 4 KB fully contiguous stores.
// ---------------------------------------------------------------------------
__global__ __launch_bounds__(256) void k_pack(const float* __restrict__ adj,
                                              float* __restrict__ deg,
                                              unsigned int* __restrict__ packed) {
  const int cb = blockIdx.x >> 5;
  const int jb = blockIdx.x & 31;
  const int col0 = cb * 1024 + threadIdx.x * 4;
  const int j0 = jb * 512;
  int cnt0 = 0, cnt1 = 0, cnt2 = 0, cnt3 = 0;

  u32x4 vv0[4], vv1[4], vv2[4], vv3[4];

#pragma unroll
  for (int seg = 0; seg < 4; ++seg) {
#pragma unroll
    for (int q = 0; q < 4; ++q) {
      unsigned int w0 = 0, w1 = 0, w2 = 0, w3 = 0;
      const float* base = adj + (size_t)(j0 + seg * 128 + q * 32) * GN + col0;
#pragma unroll 8
      for (int b = 0; b < 32; ++b) {
        f32x4 a = *(const f32x4*)(base + (size_t)b * GN);
        unsigned int m = 1u << b;
        if (a.x != 0.f) w0 |= m;
        if (a.y != 0.f) w1 |= m;
        if (a.z != 0.f) w2 |= m;
        if (a.w != 0.f) w3 |= m;
      }
      vv0[seg][q] = w0; vv1[seg][q] = w1; vv2[seg][q] = w2; vv3[seg][q] = w3;
      cnt0 += __popc(w0); cnt1 += __popc(w1); cnt2 += __popc(w2); cnt3 += __popc(w3);
    }
  }
  // quad-major stores: 4 KB contiguous per wave per seg
#pragma unroll
  for (int seg = 0; seg < 4; ++seg) {
    unsigned int* q0 = packed + ((size_t)(jb * 4 + seg) * GN + col0) * 4;
    *(u32x4*)(q0 + 0)  = vv0[seg];
    *(u32x4*)(q0 + 4)  = vv1[seg];
    *(u32x4*)(q0 + 8)  = vv2[seg];
    *(u32x4*)(q0 + 12) = vv3[seg];
  }

  atomicAdd(&deg[col0 + 0], (float)cnt0);
  atomicAdd(&deg[col0 + 1], (float)cnt1);
  atomicAdd(&deg[col0 + 2], (float)cnt2);
  atomicAdd(&deg[col0 + 3], (float)cnt3);
}

// ---------------------------------------------------------------------------
// K2 (R16/R17): z row-major bf16 + lane-linear chunked z2.
// ---------------------------------------------------------------------------
__global__ __launch_bounds__(256) void k_z(const float* __restrict__ x,
                                           const float* __restrict__ W,
                                           const float* __restrict__ deg,
                                           float* __restrict__ dinv,
                                           unsigned short* __restrict__ z_rm,
                                           unsigned short* __restrict__ z2) {
  __shared__ float Wl[64][64];
  __shared__ float xl[64][64];
  const int tid = threadIdx.x;
  const int f = tid & 63;
  const int w = tid >> 6;
  const int rowB = blockIdx.x * 64;

  for (int idx = tid; idx < 4096; idx += 256) {
    Wl[idx >> 6][idx & 63] = W[idx];
    xl[idx >> 6][idx & 63] = x[(size_t)rowB * 64 + idx];
  }
  __syncthreads();

  float acc[16];
#pragma unroll
  for (int r = 0; r < 16; ++r) acc[r] = 0.f;
  for (int k = 0; k < 64; ++k) {
    float wk = Wl[k][f];
#pragma unroll
    for (int r = 0; r < 16; ++r) acc[r] = fmaf(xl[w * 16 + r][k], wk, acc[r]);
  }

  const int row0 = rowB + w * 16;
  if (f < 16) {
    int row = row0 + f;
    dinv[row] = 1.0f / sqrtf(deg[row] + 1.0f);
  }

  unsigned short zs[16];
#pragma unroll
  for (int r = 0; r < 16; ++r) {
    int row = row0 + r;
    float di = 1.0f / sqrtf(deg[row] + 1.0f);
    unsigned short zb = f2bf(di * acc[r]);
    zs[r] = zb;
    z_rm[(size_t)row * GF + f] = zb;
  }
  unsigned int p[8];
#pragma unroll
  for (int i = 0; i < 8; ++i)
    p[i] = (unsigned int)zs[2 * i] | ((unsigned int)zs[2 * i + 1] << 16);
  // lane-linear layout: jj = (w&1)*16 + r -> kb = 2*(w&1) + (r>>3), e = r&7
  char* dst = (char*)z2 + (size_t)((rowB >> 5) + (w >> 1)) * 4096 +
              (f >> 4) * 1024 + ((2 * (w & 1)) * 16 + (f & 15)) * 16;
  u32x4 lo = {p[0], p[1], p[2], p[3]};
  u32x4 hi = {p[4], p[5], p[6], p[7]};
  *(u32x4*)dst = lo;          // kb = 2*(w&1)     (r 0..7)
  *(u32x4*)(dst + 256) = hi;  // kb = 2*(w&1) + 1 (r 8..15)
}

// ---------------------------------------------------------------------------
// K3 v13 (R17, best measured): setprio + lane-linear z2 + quad-major bits.
// ---------------------------------------------------------------------------
__global__ __launch_bounds__(512) void k_spmm(const unsigned int* __restrict__ packed,
                                              const unsigned short* __restrict__ z2,
                                              const unsigned short* __restrict__ z_rm,
                                              const float* __restrict__ dinv,
                                              const float* __restrict__ bias,
                                              float* __restrict__ out) {
  __shared__ float red[4][64][64];  // 64 KB
  const int i0 = blockIdx.x * 64;
  const int tid = threadIdx.x;
  const int wid = tid >> 6, lane = tid & 63;
  const int lrow = lane & 15, kb = lane >> 4;
  const int sh = kb * 8;

  f32x4 acc[4][4];
#pragma unroll
  for (int m = 0; m < 4; ++m)
#pragma unroll
    for (int n = 0; n < 4; ++n) acc[m][n] = (f32x4){0.f, 0.f, 0.f, 0.f};

  const size_t qstep = (size_t)GN * 4;  // dwords per quad-row
  const unsigned int* pr0 = packed + (size_t)(wid * 16) * qstep / 4 * 4 +
                            (size_t)(i0 + 0 * 16 + lrow) * 4;
  const unsigned int* pr1 = packed + (size_t)(wid * 16) * qstep / 4 * 4 +
                            (size_t)(i0 + 1 * 16 + lrow) * 4;
  const unsigned int* pr2 = packed + (size_t)(wid * 16) * qstep / 4 * 4 +
                            (size_t)(i0 + 2 * 16 + lrow) * 4;
  const unsigned int* pr3 = packed + (size_t)(wid * 16) * qstep / 4 * 4 +
                            (size_t)(i0 + 3 * 16 + lrow) * 4;
  const char* zbase = (const char*)z2 + (size_t)(wid * 64) * 4096 + lane * 16;

  bf16x8 cur0 = *(const bf16x8*)(zbase + 0 * 1024);
  bf16x8 cur1 = *(const bf16x8*)(zbase + 1 * 1024);
  bf16x8 cur2 = *(const bf16x8*)(zbase + 2 * 1024);
  bf16x8 cur3 = *(const bf16x8*)(zbase + 3 * 1024);
  u32x4 bits0 = *(const u32x4*)pr0;
  u32x4 bits1 = *(const u32x4*)pr1;
  u32x4 bits2 = *(const u32x4*)pr2;
  u32x4 bits3 = *(const u32x4*)pr3;

  for (int it = 0; it < 16; ++it) {
    // bits prefetch, one quad-row (= next iter) ahead; tail over-read lands
    // in the 512 KB ws slack after packed.
    u32x4 nb0 = *(const u32x4*)(pr0 + qstep);
    u32x4 nb1 = *(const u32x4*)(pr1 + qstep);
    u32x4 nb2 = *(const u32x4*)(pr2 + qstep);
    u32x4 nb3 = *(const u32x4*)(pr3 + qstep);
#pragma unroll
    for (int s = 0; s < 4; ++s) {
      // z prefetch for next chunk (tail lands in mapped packed; unused)
      const char* zn = zbase + (s + 1) * 4096;
      bf16x8 n0 = *(const bf16x8*)(zn + 0 * 1024);
      bf16x8 n1 = *(const bf16x8*)(zn + 1 * 1024);
      bf16x8 n2 = *(const bf16x8*)(zn + 2 * 1024);
      bf16x8 n3 = *(const bf16x8*)(zn + 3 * 1024);

      __builtin_amdgcn_s_setprio(1);
      bf16x8 a0 = decode8(bits0[s] >> sh);
      acc[0][0] = __builtin_amdgcn_mfma_f32_16x16x32_bf16(a0, cur0, acc[0][0], 0, 0, 0);
      acc[0][1] = __builtin_amdgcn_mfma_f32_16x16x32_bf16(a0, cur1, acc[0][1], 0, 0, 0);
      acc[0][2] = __builtin_amdgcn_mfma_f32_16x16x32_bf16(a0, cur2, acc[0][2], 0, 0, 0);
      acc[0][3] = __builtin_amdgcn_mfma_f32_16x16x32_bf16(a0, cur3, acc[0][3], 0, 0, 0);
      bf16x8 a1 = decode8(bits1[s] >> sh);
      acc[1][0] = __builtin_amdgcn_mfma_f32_16x16x32_bf16(a1, cur0, acc[1][0], 0, 0, 0);
      acc[1][1] = __builtin_amdgcn_mfma_f32_16x16x32_bf16(a1, cur1, acc[1][1], 0, 0, 0);
      acc[1][2] = __builtin_amdgcn_mfma_f32_16x16x32_bf16(a1, cur2, acc[1][2], 0, 0, 0);
      acc[1][3] = __builtin_amdgcn_mfma_f32_16x16x32_bf16(a1, cur3, acc[1][3], 0, 0, 0);
      bf16x8 a2 = decode8(bits2[s] >> sh);
      acc[2][0] = __builtin_amdgcn_mfma_f32_16x16x32_bf16(a2, cur0, acc[2][0], 0, 0, 0);
      acc[2][1] = __builtin_amdgcn_mfma_f32_16x16x32_bf16(a2, cur1, acc[2][1], 0, 0, 0);
      acc[2][2] = __builtin_amdgcn_mfma_f32_16x16x32_bf16(a2, cur2, acc[2][2], 0, 0, 0);
      acc[2][3] = __builtin_amdgcn_mfma_f32_16x16x32_bf16(a2, cur3, acc[2][3], 0, 0, 0);
      bf16x8 a3 = decode8(bits3[s] >> sh);
      acc[3][0] = __builtin_amdgcn_mfma_f32_16x16x32_bf16(a3, cur0, acc[3][0], 0, 0, 0);
      acc[3][1] = __builtin_amdgcn_mfma_f32_16x16x32_bf16(a3, cur1, acc[3][1], 0, 0, 0);
      acc[3][2] = __builtin_amdgcn_mfma_f32_16x16x32_bf16(a3, cur2, acc[3][2], 0, 0, 0);
      acc[3][3] = __builtin_amdgcn_mfma_f32_16x16x32_bf16(a3, cur3, acc[3][3], 0, 0, 0);
      __builtin_amdgcn_s_setprio(0);

      cur0 = n0; cur1 = n1; cur2 = n2; cur3 = n3;
    }
    bits0 = nb0; bits1 = nb1; bits2 = nb2; bits3 = nb3;
    pr0 += qstep; pr1 += qstep; pr2 += qstep; pr3 += qstep;
    zbase += 16384;
  }

  if (wid < 4) {
#pragma unroll
    for (int m = 0; m < 4; ++m)
#pragma unroll
      for (int n = 0; n < 4; ++n)
#pragma unroll
        for (int r = 0; r < 4; ++r)
          red[wid][m * 16 + kb * 4 + r][n * 16 + lrow] = acc[m][n][r];
  }
  __syncthreads();
  if (wid >= 4) {
#pragma unroll
    for (int m = 0; m < 4; ++m)
#pragma unroll
      for (int n = 0; n < 4; ++n)
#pragma unroll
        for (int r = 0; r < 4; ++r)
          red[wid - 4][m * 16 + kb * 4 + r][n * 16 + lrow] += acc[m][n][r];
  }
  __syncthreads();

  const int c = tid & 63;
  const int rg = tid >> 6;
  const float bc = bias[c];
#pragma unroll
  for (int rr = 0; rr < 8; ++rr) {
    int r = rg * 8 + rr;
    int i = i0 + r;
    float s = red[0][r][c] + red[1][r][c] + red[2][r][c] + red[3][r][c];
    float o = dinv[i] * (s + bf2f(z_rm[(size_t)i * GF + c])) + bc;
    out[(size_t)i * GF + c] = fmaxf(o, 0.f);
  }
}

// ---------------------------------------------------------------------------
extern "C" void kernel_launch(void* const* d_in, const int* in_sizes, int n_in,
                              void* d_out, int out_size, void* d_ws, size_t ws_size,
                              hipStream_t stream) {
  const float* x = (const float*)d_in[0];
  const float* adj = (const float*)d_in[1];
  const float* W = (const float*)d_in[2];
  const float* bias = (const float*)d_in[3];
  float* out = (float*)d_out;

  char* ws = (char*)d_ws;
  float* deg = (float*)ws;                                        // 64 KB
  float* dinv = (float*)(ws + 65536);                             // 64 KB
  unsigned short* z_rm = (unsigned short*)(ws + 131072);          // 2 MB
  unsigned short* z2 = (unsigned short*)(ws + 131072 + 2097152);  // 2 MB lane-linear
  unsigned int* packed = (unsigned int*)(ws + 131072 + 4194304);  // 32 MB quad-major
  // need: 131072 + 4 MB + 32 MB + 512 KB tail-prefetch slack = 38,928,384 B
  if (ws_size < 38928384u) return;

  hipMemsetAsync(deg, 0, GN * sizeof(float), stream);
  k_pack<<<dim3(512), dim3(256), 0, stream>>>(adj, deg, packed);
  k_z<<<dim3(GN / 64), dim3(256), 0, stream>>>(x, W, deg, dinv, z_rm, z2);
  k_spmm<<<dim3(GN / 64), dim3(512), 0, stream>>>(packed, z2, z_rm, dinv, bias, out);
}